// Round 12
// baseline (67.767 us; speedup 1.0000x reference)
//
#include <hip/hip_runtime.h>
#include <math.h>

#define BATCH 16
#define DIM 512
#define NPTS 1024

typedef __attribute__((ext_vector_type(8))) short short8;
typedef __attribute__((ext_vector_type(4))) float f32x4;

// ---------------------------------------------------------------------------
// helpers
// ---------------------------------------------------------------------------
__device__ __forceinline__ unsigned short f2bf(float x) {
    unsigned u = __float_as_uint(x);
    unsigned r = (u + 0x7FFFu + ((u >> 16) & 1u)) >> 16;
    return (unsigned short)r;
}

__device__ __forceinline__ void load_lds16(const void* g, void* l) {
    __builtin_amdgcn_global_load_lds(
        (const __attribute__((address_space(1))) void*)g,
        (__attribute__((address_space(3))) void*)l, 16, 0, 0);
}

// Shared Kabsch-from-H (double Jacobi eigendecomp of H^T H), writes R row a
// and t for batch b.
__device__ void kabsch_from_H(double H[3][3], const double sm[3], const double cm[3],
                              float* out, int b) {
    double C[3][3];
    for (int i = 0; i < 3; ++i)
        for (int j = 0; j < 3; ++j) {
            double s = 0;
            for (int k = 0; k < 3; ++k) s += H[k][i] * H[k][j];
            C[i][j] = s;
        }
    double V[3][3] = {{1, 0, 0}, {0, 1, 0}, {0, 0, 1}};
    for (int sweep = 0; sweep < 30; ++sweep) {
        const double offd = fabs(C[0][1]) + fabs(C[0][2]) + fabs(C[1][2]);
        const double diag = fabs(C[0][0]) + fabs(C[1][1]) + fabs(C[2][2]);
        if (offd <= 1e-15 * (diag + 1e-300)) break;
        for (int pq = 0; pq < 3; ++pq) {
            const int p = (pq == 2) ? 1 : 0;
            const int q = (pq == 0) ? 1 : 2;
            const double apq = C[p][q];
            if (fabs(apq) < 1e-300) continue;
            const double theta = (C[q][q] - C[p][p]) / (2.0 * apq);
            const double t_ = copysign(1.0, theta) / (fabs(theta) + sqrt(1.0 + theta * theta));
            const double c_ = 1.0 / sqrt(1.0 + t_ * t_);
            const double s_ = t_ * c_;
            const int r = 3 - p - q;
            const double cpp = C[p][p], cqq = C[q][q];
            C[p][p] = cpp - t_ * apq;
            C[q][q] = cqq + t_ * apq;
            C[p][q] = C[q][p] = 0.0;
            const double crp = C[r][p], crq = C[r][q];
            C[r][p] = C[p][r] = c_ * crp - s_ * crq;
            C[r][q] = C[q][r] = s_ * crp + c_ * crq;
            for (int k = 0; k < 3; ++k) {
                const double vkp = V[k][p], vkq = V[k][q];
                V[k][p] = c_ * vkp - s_ * vkq;
                V[k][q] = s_ * vkp + c_ * vkq;
            }
        }
    }
    double lam[3] = {C[0][0], C[1][1], C[2][2]};
    int i0 = 0, i1 = 1, i2 = 2, tswp;
    if (lam[i0] < lam[i1]) { tswp = i0; i0 = i1; i1 = tswp; }
    if (lam[i0] < lam[i2]) { tswp = i0; i0 = i2; i2 = tswp; }
    if (lam[i1] < lam[i2]) { tswp = i1; i1 = i2; i2 = tswp; }

    const double v0[3] = {V[0][i0], V[1][i0], V[2][i0]};
    const double v1[3] = {V[0][i1], V[1][i1], V[2][i1]};
    const double v2[3] = {V[0][i2], V[1][i2], V[2][i2]};
    const double detV = v0[0] * (v1[1] * v2[2] - v1[2] * v2[1])
                      - v0[1] * (v1[0] * v2[2] - v1[2] * v2[0])
                      + v0[2] * (v1[0] * v2[1] - v1[1] * v2[0]);

    double u0[3], u1[3], u2[3];
    for (int i = 0; i < 3; ++i)
        u0[i] = H[i][0] * v0[0] + H[i][1] * v0[1] + H[i][2] * v0[2];
    double n0 = sqrt(u0[0] * u0[0] + u0[1] * u0[1] + u0[2] * u0[2]);
    n0 = fmax(n0, 1e-300);
    u0[0] /= n0; u0[1] /= n0; u0[2] /= n0;
    for (int i = 0; i < 3; ++i)
        u1[i] = H[i][0] * v1[0] + H[i][1] * v1[1] + H[i][2] * v1[2];
    const double d01 = u0[0] * u1[0] + u0[1] * u1[1] + u0[2] * u1[2];
    u1[0] -= d01 * u0[0]; u1[1] -= d01 * u0[1]; u1[2] -= d01 * u0[2];
    double n1 = sqrt(u1[0] * u1[0] + u1[1] * u1[1] + u1[2] * u1[2]);
    n1 = fmax(n1, 1e-300);
    u1[0] /= n1; u1[1] /= n1; u1[2] /= n1;
    u2[0] = u0[1] * u1[2] - u0[2] * u1[1];
    u2[1] = u0[2] * u1[0] - u0[0] * u1[2];
    u2[2] = u0[0] * u1[1] - u0[1] * u1[0];

    double R[3][3];
    for (int a = 0; a < 3; ++a)
        for (int c = 0; c < 3; ++c)
            R[a][c] = v0[a] * u0[c] + v1[a] * u1[c] + detV * v2[a] * u2[c];

    for (int a = 0; a < 3; ++a) {
        const double tv = cm[a] - (R[a][0] * sm[0] + R[a][1] * sm[1] + R[a][2] * sm[2]);
        out[b * 9 + a * 3 + 0] = (float)R[a][0];
        out[b * 9 + a * 3 + 1] = (float)R[a][1];
        out[b * 9 + a * 3 + 2] = (float)R[a][2];
        out[BATCH * 9 + b * 3 + a] = (float)tv;
    }
}

// ---------------------------------------------------------------------------
// Kernel A: transpose+convert [b][d][n] f32 -> [b][n][d] bf16.
// One tensor-pass per block: grid 2 x 16b x 8dt x 16nt = 4096 blocks of 256.
// ---------------------------------------------------------------------------
__global__ __launch_bounds__(256) void transpose_bf16_kernel(
    const float* __restrict__ src_emb, const float* __restrict__ tgt_emb,
    unsigned short* __restrict__ AT, unsigned short* __restrict__ BT)
{
    const int bid = blockIdx.x;
    const int pass = bid & 1;
    const int r2 = bid >> 1;
    const int b  = r2 >> 7;
    const int dt = (r2 >> 4) & 7;
    const int nt = r2 & 15;
    const int tid = threadIdx.x;

    __shared__ float tile[64][65];

    const float* src = pass ? tgt_emb : src_emb;
    unsigned short* dst = pass ? BT : AT;

    // load 64 d-rows x 64 n (coalesced float4)
    const int lr = tid >> 4;          // 0..15
    const int c4 = (tid & 15) * 4;
#pragma unroll
    for (int q = 0; q < 4; ++q) {
        const int dl = lr + q * 16;
        const float4 v = *(const float4*)(src + ((size_t)(b * DIM + dt * 64 + dl)) * NPTS + nt * 64 + c4);
        tile[dl][c4 + 0] = v.x;
        tile[dl][c4 + 1] = v.y;
        tile[dl][c4 + 2] = v.z;
        tile[dl][c4 + 3] = v.w;
    }
    __syncthreads();

    // write: 2 x 16B per thread, coalesced over d
#pragma unroll
    for (int s = 0; s < 2; ++s) {
        const int nl = s * 32 + (tid >> 3);   // 0..63
        const int d8 = (tid & 7) * 8;
        union { unsigned short us[8]; uint4 q4; } pk;
#pragma unroll
        for (int k = 0; k < 8; ++k) pk.us[k] = f2bf(tile[d8 + k][nl]);
        *(uint4*)(dst + ((size_t)(b * NPTS + nt * 64 + nl)) * DIM + dt * 64 + d8) = pk.q4;
    }
}

// ---------------------------------------------------------------------------
// Kernel B: MFMA attention, ring-6 deep-prefetch pipeline (120 KB LDS,
// deliberately 1 WG/CU — R6-R8 proved TLP doesn't help; trade it for depth).
// Stage-ahead 5 chunks: cover ~1250 cyc > HBM-miss 900 cyc, so the
// barrier-coupled per-chunk load stall (the R5-R11 plateau) disappears.
// vmcnt: prologue 25 in flight; steady vmcnt(20); tail 15/10/5/0.
// XCD swizzle: bid&7 -> XCD (qt-WGs sharing a (b,ms) B-slice on one XCD).
// Swapped operands mfma(K, Q): lane registers hold P[key][query].
// P[b][p][v][n], p = ms*4+wave, v in {l, a0, a1, a2}
// ---------------------------------------------------------------------------
#define AB_BYTES 4096           // 64 rows x 32 bf16 (64B rows)
#define BB_BYTES 16384          // 256 rows x 64B
#define NRING 6

__global__ __launch_bounds__(256) void attn_corr_kernel(
    const unsigned short* __restrict__ AT, const unsigned short* __restrict__ BT,
    const float* __restrict__ tgt, const float* __restrict__ temperature,
    float* __restrict__ P)
{
    __shared__ char lds[NRING * (AB_BYTES + BB_BYTES)];   // 120 KB -> 1 WG/CU

    const int bid = blockIdx.x;
    const int slice = bid & 7;        // XCD id under round-robin dispatch
    const int j     = bid >> 3;       // 0..127, consecutive within an XCD
    const int pair  = j >> 4;         // 0..7
    const int qt    = j & 15;         // query tile
    const int pidx  = slice * 8 + pair;   // 0..63 -> (b, ms)
    const int b     = pidx >> 2;
    const int ms    = pidx & 3;

    const int tid = threadIdx.x;
    const int lane = tid & 63;
    const int wv = tid >> 6;

    const unsigned short* Abase = AT + ((size_t)b * NPTS + qt * 64) * DIM;
    const unsigned short* Bbase = BT + ((size_t)b * NPTS + ms * 256) * DIM;

    // staging lane->row/slot decode (32-d chunks, 64B rows, slot swizzle s^((r>>1)&3))
    const int a_r  = wv * 16 + (lane >> 2);       // A row 0..63
    const int a_cl = (lane & 3) ^ ((a_r >> 1) & 3);
    const size_t a_src_off = (size_t)a_r * DIM + a_cl * 8;

    int b_r[4], b_cl[4];
#pragma unroll
    for (int q = 0; q < 4; ++q) {
        b_r[q]  = q * 64 + wv * 16 + (lane >> 2);  // B row 0..255
        b_cl[q] = (lane & 3) ^ ((b_r[q] >> 1) & 3);
    }

    const int fp = lane & 15;     // frag row-within-16
    const int fg = lane >> 4;     // frag k-group (8 bf16 = 16B slot)

    // ---- preload tgt values + temperature BEFORE the pipeline (12 oldest
    // loads; drained by the first vmcnt(20) together with stage-0) ----
    const float s2 = temperature[b] * (0.04419417382415922f * 1.4426950408889634f);
    const float* tb = tgt + (size_t)b * 3 * NPTS;
    float tv0[4][4], tv1[4][4], tv2[4][4];
#pragma unroll
    for (int kt = 0; kt < 4; ++kt)
#pragma unroll
        for (int reg = 0; reg < 4; ++reg) {
            const int m = ms * 256 + wv * 64 + kt * 16 + fg * 4 + reg;
            tv0[kt][reg] = tb[m];
            tv1[kt][reg] = tb[NPTS + m];
            tv2[kt][reg] = tb[2 * NPTS + m];
        }
    __builtin_amdgcn_sched_barrier(0);

    // acc[kt][qj]: D[key = kt*16 + fg*4 + reg][query = qj*16 + fp]
    f32x4 acc[4][4];
#pragma unroll
    for (int kt = 0; kt < 4; ++kt)
#pragma unroll
        for (int qj = 0; qj < 4; ++qj) acc[kt][qj] = (f32x4){0.f, 0.f, 0.f, 0.f};

    char* AbP[NRING];
    char* BbP[NRING];
#pragma unroll
    for (int r = 0; r < NRING; ++r) {
        AbP[r] = lds + r * AB_BYTES;
        BbP[r] = lds + NRING * AB_BYTES + r * BB_BYTES;
    }

#define STAGE(CH, ABUF, BBUF)                                                        \
    {                                                                                \
        const int d0_ = (CH) * 32;                                                   \
        load_lds16(Abase + a_src_off + d0_, (ABUF) + wv * 1024);                     \
        _Pragma("unroll")                                                            \
        for (int q = 0; q < 4; ++q)                                                  \
            load_lds16(Bbase + (size_t)b_r[q] * DIM + d0_ + b_cl[q] * 8,             \
                       (BBUF) + q * 4096 + wv * 1024);                               \
    }

#define COMPUTE(ABUF, BBUF)                                                          \
    {                                                                                \
        short8 kf[4], qf[4];                                                         \
        _Pragma("unroll")                                                            \
        for (int kt = 0; kt < 4; ++kt) {                                             \
            const int r = wv * 64 + kt * 16 + fp;                                    \
            const int cl = fg ^ ((r >> 1) & 3);                                      \
            kf[kt] = *(const short8*)((BBUF) + r * 64 + cl * 16);                    \
        }                                                                            \
        _Pragma("unroll")                                                            \
        for (int qj = 0; qj < 4; ++qj) {                                             \
            const int r = qj * 16 + fp;                                              \
            const int cl = fg ^ ((r >> 1) & 3);                                      \
            qf[qj] = *(const short8*)((ABUF) + r * 64 + cl * 16);                    \
        }                                                                            \
        __builtin_amdgcn_s_setprio(1);                                               \
        _Pragma("unroll")                                                            \
        for (int kt = 0; kt < 4; ++kt)                                               \
            _Pragma("unroll")                                                        \
            for (int qj = 0; qj < 4; ++qj)                                           \
                acc[kt][qj] = __builtin_amdgcn_mfma_f32_16x16x32_bf16(               \
                    kf[kt], qf[qj], acc[kt][qj], 0, 0, 0);                           \
        __builtin_amdgcn_s_setprio(0);                                               \
    }

    // prologue: stage chunks 0..4 (25 staging loads in flight per wave)
    STAGE(0, AbP[0], BbP[0]);
    STAGE(1, AbP[1], BbP[1]);
    STAGE(2, AbP[2], BbP[2]);
    STAGE(3, AbP[3], BbP[3]);
    STAGE(4, AbP[4], BbP[4]);

    // steady state per chunk ch:
    //   vmcnt(min(20,(15-ch)*5)): own stage(ch) drained, rest in flight.
    //   barrier: all waves' ch data in LDS AND compute(ch-1) done
    //            -> buf[(ch+5)%6] free; stage(ch+5) there; compute(ch).
#pragma unroll
    for (int ch = 0; ch < 16; ++ch) {
        if (ch <= 11)      { asm volatile("s_waitcnt vmcnt(20)" ::: "memory"); }
        else if (ch == 12) { asm volatile("s_waitcnt vmcnt(15)" ::: "memory"); }
        else if (ch == 13) { asm volatile("s_waitcnt vmcnt(10)" ::: "memory"); }
        else if (ch == 14) { asm volatile("s_waitcnt vmcnt(5)"  ::: "memory"); }
        else               { asm volatile("s_waitcnt vmcnt(0)"  ::: "memory"); }
        __builtin_amdgcn_s_barrier();
        __builtin_amdgcn_sched_barrier(0);
        if (ch + 5 < 16) STAGE(ch + 5, AbP[(ch + 5) % NRING], BbP[(ch + 5) % NRING]);
        COMPUTE(AbP[ch % NRING], BbP[ch % NRING]);
        __builtin_amdgcn_sched_barrier(0);
    }

    // ---- max-free softmax partials over this wave's 64 keys (in-register) ----
    float l[4]  = {0.f, 0.f, 0.f, 0.f};
    float a0[4] = {0.f, 0.f, 0.f, 0.f};
    float a1[4] = {0.f, 0.f, 0.f, 0.f};
    float a2[4] = {0.f, 0.f, 0.f, 0.f};

#pragma unroll
    for (int kt = 0; kt < 4; ++kt) {
#pragma unroll
        for (int qj = 0; qj < 4; ++qj) {
#pragma unroll
            for (int reg = 0; reg < 4; ++reg) {
                const float w = exp2f(acc[kt][qj][reg] * s2);
                l[qj]  += w;
                a0[qj] = fmaf(w, tv0[kt][reg], a0[qj]);
                a1[qj] = fmaf(w, tv1[kt][reg], a1[qj]);
                a2[qj] = fmaf(w, tv2[kt][reg], a2[qj]);
            }
        }
    }

    float* Pb = P + ((size_t)b * 16 + (ms * 4 + wv)) * 4 * NPTS;
#pragma unroll
    for (int qj = 0; qj < 4; ++qj) {
        float lv = l[qj], v0 = a0[qj], v1 = a1[qj], v2 = a2[qj];
        lv += __shfl_xor(lv, 16); lv += __shfl_xor(lv, 32);
        v0 += __shfl_xor(v0, 16); v0 += __shfl_xor(v0, 32);
        v1 += __shfl_xor(v1, 16); v1 += __shfl_xor(v1, 32);
        v2 += __shfl_xor(v2, 16); v2 += __shfl_xor(v2, 32);
        if (fg == 0) {
            const int n = qt * 64 + qj * 16 + fp;
            Pb[0 * NPTS + n] = lv;
            Pb[1 * NPTS + n] = v0;
            Pb[2 * NPTS + n] = v1;
            Pb[3 * NPTS + n] = v2;
        }
    }
}

// ---------------------------------------------------------------------------
// Kernel C1: merge partials -> corr; per-block raw sums (Σs, Σc, Σ s·cᵀ).
// 64 blocks (4 per batch). H = Σ s·cᵀ − N·sm·cmᵀ assembled later in double.
// ---------------------------------------------------------------------------
__global__ __launch_bounds__(256) void merge_partial_kernel(
    const float* __restrict__ P, const float* __restrict__ src,
    float* __restrict__ Pacc)
{
    const int bid = blockIdx.x;
    const int b   = bid >> 2;
    const int seg = bid & 3;
    const int tid = threadIdx.x;
    const int n   = seg * 256 + tid;

    const float* Pb = P + (size_t)b * 16 * 4 * NPTS;
    float l = 0, a0 = 0, a1 = 0, a2 = 0;
    for (int pp = 0; pp < 16; ++pp) {
        const float* q = Pb + (size_t)pp * 4 * NPTS;
        l  += q[n];
        a0 += q[NPTS + n];
        a1 += q[2 * NPTS + n];
        a2 += q[3 * NPTS + n];
    }
    const float inv = 1.0f / l;
    const float c0 = a0 * inv, c1 = a1 * inv, c2 = a2 * inv;

    const float* sp = src + (size_t)b * 3 * NPTS;
    const float s0 = sp[n], s1 = sp[NPTS + n], s2 = sp[2 * NPTS + n];

    float v[15] = { s0, s1, s2, c0, c1, c2,
                    s0 * c0, s0 * c1, s0 * c2,
                    s1 * c0, s1 * c1, s1 * c2,
                    s2 * c0, s2 * c1, s2 * c2 };

#pragma unroll
    for (int off = 1; off < 64; off <<= 1)
#pragma unroll
        for (int k = 0; k < 15; ++k) v[k] += __shfl_xor(v[k], off);

    __shared__ float red[4][15];
    const int wv = tid >> 6;
    if ((tid & 63) == 0)
#pragma unroll
        for (int k = 0; k < 15; ++k) red[wv][k] = v[k];
    __syncthreads();
    if (tid < 15)
        Pacc[bid * 15 + tid] = red[0][tid] + red[1][tid] + red[2][tid] + red[3][tid];
}

// ---------------------------------------------------------------------------
// Kernel C2: final per-batch assembly (double) + Kabsch SVD. 16 tiny blocks.
// ---------------------------------------------------------------------------
__global__ __launch_bounds__(64) void svd_final_kernel(
    const float* __restrict__ Pacc, float* __restrict__ out)
{
    const int b = blockIdx.x;
    if (threadIdx.x != 0) return;

    double s[15];
    for (int k = 0; k < 15; ++k) {
        double acc = 0;
        for (int seg = 0; seg < 4; ++seg)
            acc += (double)Pacc[(b * 4 + seg) * 15 + k];
        s[k] = acc;
    }
    const double invN = 1.0 / (double)NPTS;
    const double sm[3] = {s[0] * invN, s[1] * invN, s[2] * invN};
    const double cm[3] = {s[3] * invN, s[4] * invN, s[5] * invN};
    double H[3][3];
    for (int i = 0; i < 3; ++i)
        for (int jj = 0; jj < 3; ++jj)
            H[i][jj] = s[6 + i * 3 + jj] - (double)NPTS * sm[i] * cm[jj];
    kabsch_from_H(H, sm, cm, out, b);
}

// ---------------------------------------------------------------------------
// Legacy fp32 path (fallback when ws is too small for the bf16 pipeline)
// ---------------------------------------------------------------------------
__global__ __launch_bounds__(256) void flash_corr_kernel(
    const float* __restrict__ src_emb,
    const float* __restrict__ tgt_emb,
    const float* __restrict__ tgt,
    const float* __restrict__ temperature,
    float* __restrict__ corr)
{
    const int bid = blockIdx.x;
    const int b   = bid & 15;
    const int qt  = bid >> 4;
    const int n0  = qt * 64;
    const int tid = threadIdx.x;
    const int tx  = tid & 15;
    const int ty  = tid >> 4;

    const float scale = temperature[b] * (1.0f / sqrtf((float)DIM));

    __shared__ float As[2][32][64];
    __shared__ float Bs[2][32][64];
    __shared__ float Ts[3][64];

    const float* Abase  = src_emb + (size_t)b * DIM * NPTS + n0;
    const float* Bbatch = tgt_emb + (size_t)b * DIM * NPTS;
    const float* Tbatch = tgt     + (size_t)b * 3 * NPTS;

    const int dr0 = tid >> 4;
    const int dr1 = dr0 + 16;
    const int c4  = (tid & 15) * 4;

    float mrun[4], lpart[4], acc0[4], acc1[4], acc2[4];
#pragma unroll
    for (int r = 0; r < 4; ++r) {
        mrun[r] = -1e30f; lpart[r] = 0.0f;
        acc0[r] = 0.0f; acc1[r] = 0.0f; acc2[r] = 0.0f;
    }

    for (int mt = 0; mt < 16; ++mt) {
        const int m0 = mt * 64;
        const float* Bbase = Bbatch + m0;
        __syncthreads();
        if (tid < 192) {
            const int i = tid >> 6, mc = tid & 63;
            Ts[i][mc] = Tbatch[i * NPTS + m0 + mc];
        }
        {
            float4 a0 = *(const float4*)(Abase + (size_t)dr0 * NPTS + c4);
            float4 a1 = *(const float4*)(Abase + (size_t)dr1 * NPTS + c4);
            float4 b0 = *(const float4*)(Bbase + (size_t)dr0 * NPTS + c4);
            float4 b1 = *(const float4*)(Bbase + (size_t)dr1 * NPTS + c4);
            *(float4*)&As[0][dr0][c4] = a0;
            *(float4*)&As[0][dr1][c4] = a1;
            *(float4*)&Bs[0][dr0][c4] = b0;
            *(float4*)&Bs[0][dr1][c4] = b1;
        }
        __syncthreads();

        float S[4][4];
#pragma unroll
        for (int r = 0; r < 4; ++r)
#pragma unroll
            for (int c = 0; c < 4; ++c) S[r][c] = 0.0f;

        for (int ch = 0; ch < 16; ++ch) {
            const int buf = ch & 1;
            float4 a0n, a1n, b0n, b1n;
            if (ch < 15) {
                const float* Ab = Abase + (size_t)(ch + 1) * 32 * NPTS;
                const float* Bb = Bbase + (size_t)(ch + 1) * 32 * NPTS;
                a0n = *(const float4*)(Ab + (size_t)dr0 * NPTS + c4);
                a1n = *(const float4*)(Ab + (size_t)dr1 * NPTS + c4);
                b0n = *(const float4*)(Bb + (size_t)dr0 * NPTS + c4);
                b1n = *(const float4*)(Bb + (size_t)dr1 * NPTS + c4);
            }
#pragma unroll
            for (int dk = 0; dk < 32; ++dk) {
                const float4 av = *(const float4*)(&As[buf][dk][ty * 4]);
                const float4 bv = *(const float4*)(&Bs[buf][dk][tx * 4]);
                S[0][0] = fmaf(av.x, bv.x, S[0][0]);
                S[0][1] = fmaf(av.x, bv.y, S[0][1]);
                S[0][2] = fmaf(av.x, bv.z, S[0][2]);
                S[0][3] = fmaf(av.x, bv.w, S[0][3]);
                S[1][0] = fmaf(av.y, bv.x, S[1][0]);
                S[1][1] = fmaf(av.y, bv.y, S[1][1]);
                S[1][2] = fmaf(av.y, bv.z, S[1][2]);
                S[1][3] = fmaf(av.y, bv.w, S[1][3]);
                S[2][0] = fmaf(av.z, bv.x, S[2][0]);
                S[2][1] = fmaf(av.z, bv.y, S[2][1]);
                S[2][2] = fmaf(av.z, bv.z, S[2][2]);
                S[2][3] = fmaf(av.z, bv.w, S[2][3]);
                S[3][0] = fmaf(av.w, bv.x, S[3][0]);
                S[3][1] = fmaf(av.w, bv.y, S[3][1]);
                S[3][2] = fmaf(av.w, bv.z, S[3][2]);
                S[3][3] = fmaf(av.w, bv.w, S[3][3]);
            }
            __syncthreads();
            if (ch < 15) {
                *(float4*)&As[buf ^ 1][dr0][c4] = a0n;
                *(float4*)&As[buf ^ 1][dr1][c4] = a1n;
                *(float4*)&Bs[buf ^ 1][dr0][c4] = b0n;
                *(float4*)&Bs[buf ^ 1][dr1][c4] = b1n;
                __syncthreads();
            }
        }

#pragma unroll
        for (int r = 0; r < 4; ++r) {
            float z0 = S[r][0] * scale, z1 = S[r][1] * scale;
            float z2 = S[r][2] * scale, z3 = S[r][3] * scale;
            float mt_ = fmaxf(fmaxf(z0, z1), fmaxf(z2, z3));
#pragma unroll
            for (int off = 1; off < 16; off <<= 1)
                mt_ = fmaxf(mt_, __shfl_xor(mt_, off));
            const float mnew = fmaxf(mrun[r], mt_);
            const float f = expf(mrun[r] - mnew);
            lpart[r] *= f; acc0[r] *= f; acc1[r] *= f; acc2[r] *= f;
            const float w0 = expf(z0 - mnew);
            const float w1 = expf(z1 - mnew);
            const float w2 = expf(z2 - mnew);
            const float w3 = expf(z3 - mnew);
            lpart[r] += w0 + w1 + w2 + w3;
            const int mc = tx * 4;
            acc0[r] += w0 * Ts[0][mc] + w1 * Ts[0][mc+1] + w2 * Ts[0][mc+2] + w3 * Ts[0][mc+3];
            acc1[r] += w0 * Ts[1][mc] + w1 * Ts[1][mc+1] + w2 * Ts[1][mc+2] + w3 * Ts[1][mc+3];
            acc2[r] += w0 * Ts[2][mc] + w1 * Ts[2][mc+1] + w2 * Ts[2][mc+2] + w3 * Ts[2][mc+3];
            mrun[r] = mnew;
        }
    }

#pragma unroll
    for (int r = 0; r < 4; ++r) {
        float l = lpart[r], a0 = acc0[r], a1 = acc1[r], a2 = acc2[r];
#pragma unroll
        for (int off = 1; off < 16; off <<= 1) {
            l  += __shfl_xor(l,  off);
            a0 += __shfl_xor(a0, off);
            a1 += __shfl_xor(a1, off);
            a2 += __shfl_xor(a2, off);
        }
        if (tx == 0) {
            const int n = n0 + ty * 4 + r;
            const float inv = 1.0f / l;
            corr[((size_t)b * 3 + 0) * NPTS + n] = a0 * inv;
            corr[((size_t)b * 3 + 1) * NPTS + n] = a1 * inv;
            corr[((size_t)b * 3 + 2) * NPTS + n] = a2 * inv;
        }
    }
}

__global__ __launch_bounds__(256) void reduce_svd_kernel(
    const float* __restrict__ src,
    const float* __restrict__ corr,
    float* __restrict__ out)
{
    const int b = blockIdx.x;
    const int tid = threadIdx.x;

    __shared__ float wred[4][9];
    __shared__ float meansh[6];

    const float* sp = src  + (size_t)b * 3 * NPTS;
    const float* cp = corr + (size_t)b * 3 * NPTS;

    float ss0 = 0, ss1 = 0, ss2 = 0, cs0 = 0, cs1 = 0, cs2 = 0;
    for (int n = tid; n < NPTS; n += 256) {
        ss0 += sp[n]; ss1 += sp[NPTS + n]; ss2 += sp[2 * NPTS + n];
        cs0 += cp[n]; cs1 += cp[NPTS + n]; cs2 += cp[2 * NPTS + n];
    }
#pragma unroll
    for (int off = 1; off < 64; off <<= 1) {
        ss0 += __shfl_xor(ss0, off); ss1 += __shfl_xor(ss1, off); ss2 += __shfl_xor(ss2, off);
        cs0 += __shfl_xor(cs0, off); cs1 += __shfl_xor(cs1, off); cs2 += __shfl_xor(cs2, off);
    }
    const int wave = tid >> 6;
    if ((tid & 63) == 0) {
        wred[wave][0] = ss0; wred[wave][1] = ss1; wred[wave][2] = ss2;
        wred[wave][3] = cs0; wred[wave][4] = cs1; wred[wave][5] = cs2;
    }
    __syncthreads();
    if (tid < 6)
        meansh[tid] = (wred[0][tid] + wred[1][tid] + wred[2][tid] + wred[3][tid]) * (1.0f / NPTS);
    __syncthreads();
    const float sm0 = meansh[0], sm1 = meansh[1], sm2 = meansh[2];
    const float cm0 = meansh[3], cm1 = meansh[4], cm2 = meansh[5];

    float h[9] = {0, 0, 0, 0, 0, 0, 0, 0, 0};
    for (int n = tid; n < NPTS; n += 256) {
        const float a0 = sp[n] - sm0, a1 = sp[NPTS + n] - sm1, a2 = sp[2 * NPTS + n] - sm2;
        const float b0 = cp[n] - cm0, b1 = cp[NPTS + n] - cm1, b2 = cp[2 * NPTS + n] - cm2;
        h[0] += a0 * b0; h[1] += a0 * b1; h[2] += a0 * b2;
        h[3] += a1 * b0; h[4] += a1 * b1; h[5] += a1 * b2;
        h[6] += a2 * b0; h[7] += a2 * b1; h[8] += a2 * b2;
    }
#pragma unroll
    for (int off = 1; off < 64; off <<= 1) {
#pragma unroll
        for (int j = 0; j < 9; ++j) h[j] += __shfl_xor(h[j], off);
    }
    __syncthreads();
    if ((tid & 63) == 0) {
#pragma unroll
        for (int j = 0; j < 9; ++j) wred[wave][j] = h[j];
    }
    __syncthreads();

    if (tid == 0) {
        double H[3][3];
        for (int i = 0; i < 3; ++i)
            for (int j = 0; j < 3; ++j)
                H[i][j] = (double)wred[0][i * 3 + j] + wred[1][i * 3 + j]
                        + wred[2][i * 3 + j] + wred[3][i * 3 + j];
        const double sm[3] = {sm0, sm1, sm2};
        const double cm[3] = {cm0, cm1, cm2};
        kabsch_from_H(H, sm, cm, out, b);
    }
}

extern "C" void kernel_launch(void* const* d_in, const int* in_sizes, int n_in,
                              void* d_out, int out_size, void* d_ws, size_t ws_size,
                              hipStream_t stream) {
    const float* src_emb = (const float*)d_in[0];
    const float* tgt_emb = (const float*)d_in[1];
    const float* src     = (const float*)d_in[2];
    const float* tgt     = (const float*)d_in[3];
    const float* temp    = (const float*)d_in[4];
    float* out = (float*)d_out;

    const size_t AT_BYTES   = (size_t)BATCH * NPTS * DIM * 2;    // 16 MB
    const size_t P_BYTES    = (size_t)BATCH * 16 * 4 * NPTS * 4; // 4 MB
    const size_t PACC_BYTES = 64 * 15 * sizeof(float);

    if (ws_size >= 2 * AT_BYTES + P_BYTES + PACC_BYTES) {
        unsigned short* AT = (unsigned short*)d_ws;
        unsigned short* BT = (unsigned short*)((char*)d_ws + AT_BYTES);
        float* P    = (float*)((char*)d_ws + 2 * AT_BYTES);
        float* Pacc = (float*)((char*)d_ws + 2 * AT_BYTES + P_BYTES);

        transpose_bf16_kernel<<<dim3(2 * BATCH * 8 * 16), dim3(256), 0, stream>>>(
            src_emb, tgt_emb, AT, BT);
        attn_corr_kernel<<<dim3(BATCH * 16 * 4), dim3(256), 0, stream>>>(
            AT, BT, tgt, temp, P);
        merge_partial_kernel<<<dim3(64), dim3(256), 0, stream>>>(P, src, Pacc);
        svd_final_kernel<<<dim3(BATCH), dim3(64), 0, stream>>>(Pacc, out);
    } else {
        float* corr = (float*)d_ws;  // [B][3][N] fp32 = 192 KiB
        flash_corr_kernel<<<dim3(BATCH * (NPTS / 64)), dim3(256), 0, stream>>>(
            src_emb, tgt_emb, tgt, temp, corr);
        reduce_svd_kernel<<<dim3(BATCH), dim3(256), 0, stream>>>(src, corr, out);
    }
}

// Round 13
// 58.005 us; speedup vs baseline: 1.1683x; 1.1683x over previous
//
#include <hip/hip_runtime.h>
#include <math.h>

#define BATCH 16
#define DIM 512
#define NPTS 1024

typedef __attribute__((ext_vector_type(8))) short short8;
typedef __attribute__((ext_vector_type(4))) float f32x4;

// ---------------------------------------------------------------------------
// helpers
// ---------------------------------------------------------------------------
__device__ __forceinline__ unsigned short f2bf(float x) {
    unsigned u = __float_as_uint(x);
    unsigned r = (u + 0x7FFFu + ((u >> 16) & 1u)) >> 16;
    return (unsigned short)r;
}

__device__ __forceinline__ void load_lds16(const void* g, void* l) {
    __builtin_amdgcn_global_load_lds(
        (const __attribute__((address_space(1))) void*)g,
        (__attribute__((address_space(3))) void*)l, 16, 0, 0);
}

// Shared Kabsch-from-H (double Jacobi eigendecomp of H^T H), writes R row a
// and t for batch b.
__device__ void kabsch_from_H(double H[3][3], const double sm[3], const double cm[3],
                              float* out, int b) {
    double C[3][3];
    for (int i = 0; i < 3; ++i)
        for (int j = 0; j < 3; ++j) {
            double s = 0;
            for (int k = 0; k < 3; ++k) s += H[k][i] * H[k][j];
            C[i][j] = s;
        }
    double V[3][3] = {{1, 0, 0}, {0, 1, 0}, {0, 0, 1}};
    for (int sweep = 0; sweep < 30; ++sweep) {
        const double offd = fabs(C[0][1]) + fabs(C[0][2]) + fabs(C[1][2]);
        const double diag = fabs(C[0][0]) + fabs(C[1][1]) + fabs(C[2][2]);
        if (offd <= 1e-15 * (diag + 1e-300)) break;
        for (int pq = 0; pq < 3; ++pq) {
            const int p = (pq == 2) ? 1 : 0;
            const int q = (pq == 0) ? 1 : 2;
            const double apq = C[p][q];
            if (fabs(apq) < 1e-300) continue;
            const double theta = (C[q][q] - C[p][p]) / (2.0 * apq);
            const double t_ = copysign(1.0, theta) / (fabs(theta) + sqrt(1.0 + theta * theta));
            const double c_ = 1.0 / sqrt(1.0 + t_ * t_);
            const double s_ = t_ * c_;
            const int r = 3 - p - q;
            const double cpp = C[p][p], cqq = C[q][q];
            C[p][p] = cpp - t_ * apq;
            C[q][q] = cqq + t_ * apq;
            C[p][q] = C[q][p] = 0.0;
            const double crp = C[r][p], crq = C[r][q];
            C[r][p] = C[p][r] = c_ * crp - s_ * crq;
            C[r][q] = C[q][r] = s_ * crp + c_ * crq;
            for (int k = 0; k < 3; ++k) {
                const double vkp = V[k][p], vkq = V[k][q];
                V[k][p] = c_ * vkp - s_ * vkq;
                V[k][q] = s_ * vkp + c_ * vkq;
            }
        }
    }
    double lam[3] = {C[0][0], C[1][1], C[2][2]};
    int i0 = 0, i1 = 1, i2 = 2, tswp;
    if (lam[i0] < lam[i1]) { tswp = i0; i0 = i1; i1 = tswp; }
    if (lam[i0] < lam[i2]) { tswp = i0; i0 = i2; i2 = tswp; }
    if (lam[i1] < lam[i2]) { tswp = i1; i1 = i2; i2 = tswp; }

    const double v0[3] = {V[0][i0], V[1][i0], V[2][i0]};
    const double v1[3] = {V[0][i1], V[1][i1], V[2][i1]};
    const double v2[3] = {V[0][i2], V[1][i2], V[2][i2]};
    const double detV = v0[0] * (v1[1] * v2[2] - v1[2] * v2[1])
                      - v0[1] * (v1[0] * v2[2] - v1[2] * v2[0])
                      + v0[2] * (v1[0] * v2[1] - v1[1] * v2[0]);

    double u0[3], u1[3], u2[3];
    for (int i = 0; i < 3; ++i)
        u0[i] = H[i][0] * v0[0] + H[i][1] * v0[1] + H[i][2] * v0[2];
    double n0 = sqrt(u0[0] * u0[0] + u0[1] * u0[1] + u0[2] * u0[2]);
    n0 = fmax(n0, 1e-300);
    u0[0] /= n0; u0[1] /= n0; u0[2] /= n0;
    for (int i = 0; i < 3; ++i)
        u1[i] = H[i][0] * v1[0] + H[i][1] * v1[1] + H[i][2] * v1[2];
    const double d01 = u0[0] * u1[0] + u0[1] * u1[1] + u0[2] * u1[2];
    u1[0] -= d01 * u0[0]; u1[1] -= d01 * u0[1]; u1[2] -= d01 * u0[2];
    double n1 = sqrt(u1[0] * u1[0] + u1[1] * u1[1] + u1[2] * u1[2]);
    n1 = fmax(n1, 1e-300);
    u1[0] /= n1; u1[1] /= n1; u1[2] /= n1;
    u2[0] = u0[1] * u1[2] - u0[2] * u1[1];
    u2[1] = u0[2] * u1[0] - u0[0] * u1[2];
    u2[2] = u0[0] * u1[1] - u0[1] * u1[0];

    double R[3][3];
    for (int a = 0; a < 3; ++a)
        for (int c = 0; c < 3; ++c)
            R[a][c] = v0[a] * u0[c] + v1[a] * u1[c] + detV * v2[a] * u2[c];

    for (int a = 0; a < 3; ++a) {
        const double tv = cm[a] - (R[a][0] * sm[0] + R[a][1] * sm[1] + R[a][2] * sm[2]);
        out[b * 9 + a * 3 + 0] = (float)R[a][0];
        out[b * 9 + a * 3 + 1] = (float)R[a][1];
        out[b * 9 + a * 3 + 2] = (float)R[a][2];
        out[BATCH * 9 + b * 3 + a] = (float)tv;
    }
}

// ---------------------------------------------------------------------------
// Kernel A: transpose+convert [b][d][n] f32 -> [b][n][d] bf16.
// One tensor-pass per block: grid 2 x 16b x 8dt x 16nt = 4096 blocks of 256.
// ---------------------------------------------------------------------------
__global__ __launch_bounds__(256) void transpose_bf16_kernel(
    const float* __restrict__ src_emb, const float* __restrict__ tgt_emb,
    unsigned short* __restrict__ AT, unsigned short* __restrict__ BT)
{
    const int bid = blockIdx.x;
    const int pass = bid & 1;
    const int r2 = bid >> 1;
    const int b  = r2 >> 7;
    const int dt = (r2 >> 4) & 7;
    const int nt = r2 & 15;
    const int tid = threadIdx.x;

    __shared__ float tile[64][65];

    const float* src = pass ? tgt_emb : src_emb;
    unsigned short* dst = pass ? BT : AT;

    // load 64 d-rows x 64 n (coalesced float4)
    const int lr = tid >> 4;          // 0..15
    const int c4 = (tid & 15) * 4;
#pragma unroll
    for (int q = 0; q < 4; ++q) {
        const int dl = lr + q * 16;
        const float4 v = *(const float4*)(src + ((size_t)(b * DIM + dt * 64 + dl)) * NPTS + nt * 64 + c4);
        tile[dl][c4 + 0] = v.x;
        tile[dl][c4 + 1] = v.y;
        tile[dl][c4 + 2] = v.z;
        tile[dl][c4 + 3] = v.w;
    }
    __syncthreads();

    // write: 2 x 16B per thread, coalesced over d
#pragma unroll
    for (int s = 0; s < 2; ++s) {
        const int nl = s * 32 + (tid >> 3);   // 0..63
        const int d8 = (tid & 7) * 8;
        union { unsigned short us[8]; uint4 q4; } pk;
#pragma unroll
        for (int k = 0; k < 8; ++k) pk.us[k] = f2bf(tile[d8 + k][nl]);
        *(uint4*)(dst + ((size_t)(b * NPTS + nt * 64 + nl)) * DIM + dt * 64 + d8) = pk.q4;
    }
}

// ---------------------------------------------------------------------------
// Kernel B: MFMA attention, ring-3 counted-vmcnt pipeline, 128q x 256k tile.
// WG = (b, 128-query tile qt 0..7, 256-key slice ms 0..3); 4 waves, wave owns
// 64 keys x 128 queries (acc[4][8], 32 MFMA/chunk). 512 WGs.
// Ring-3 (72 KB LDS, 2 WG/CU), stage-ahead 2, ONE barrier per chunk:
//   vmcnt(6): stage(ch) drained, stage(ch+1)'s 6 in flight.
//   barrier: proves everyone's ch data staged AND compute(ch-1) done
//            -> buf[(ch+2)%3] free; stage(ch+2) there; compute(ch).
// XCD swizzle: bid&7 -> XCD (qt-WGs sharing a (b,ms) B-slice on one XCD).
// Swapped operands mfma(K, Q): lane registers hold P[key][query].
// P[b][p][v][n], p = ms*4+wave, v in {l, a0, a1, a2} (layout unchanged).
// [R12 post-mortem: ring-6/1-WG-per-CU regressed (41.5 us attn, 9.2% occ);
//  this ring-3/2-WG config is the measured best of the R5-R12 family.]
// ---------------------------------------------------------------------------
#define AB_BYTES 8192           // 128 rows x 64B
#define BB_BYTES 16384          // 256 rows x 64B

__global__ __launch_bounds__(256) void attn_corr_kernel(
    const unsigned short* __restrict__ AT, const unsigned short* __restrict__ BT,
    const float* __restrict__ tgt, const float* __restrict__ temperature,
    float* __restrict__ P)
{
    __shared__ char lds[3 * (AB_BYTES + BB_BYTES)];   // 72 KB -> 2 WG/CU

    const int bid = blockIdx.x;
    const int slice = bid & 7;        // XCD id under round-robin dispatch
    const int j     = bid >> 3;       // 0..63, consecutive within an XCD
    const int pair  = j >> 3;         // 0..7
    const int qt    = j & 7;          // query tile (128 n)
    const int pidx  = slice * 8 + pair;   // 0..63 -> (b, ms)
    const int b     = pidx >> 2;
    const int ms    = pidx & 3;

    const int tid = threadIdx.x;
    const int lane = tid & 63;
    const int wv = tid >> 6;

    const unsigned short* Abase = AT + ((size_t)b * NPTS + qt * 128) * DIM;
    const unsigned short* Bbase = BT + ((size_t)b * NPTS + ms * 256) * DIM;

    // staging lane->row/slot decode (32-d chunks, 64B rows, slot swizzle s^((r>>1)&3))
    int a_r[2], a_cl[2];
#pragma unroll
    for (int q = 0; q < 2; ++q) {
        a_r[q]  = q * 64 + wv * 16 + (lane >> 2);  // A row 0..127
        a_cl[q] = (lane & 3) ^ ((a_r[q] >> 1) & 3);
    }
    int b_r[4], b_cl[4];
#pragma unroll
    for (int q = 0; q < 4; ++q) {
        b_r[q]  = q * 64 + wv * 16 + (lane >> 2);  // B row 0..255
        b_cl[q] = (lane & 3) ^ ((b_r[q] >> 1) & 3);
    }

    const int fp = lane & 15;     // frag row-within-16
    const int fg = lane >> 4;     // frag k-group (8 bf16 = 16B slot)

    // acc[kt][qj]: D[key = kt*16 + fg*4 + reg][query = qj*16 + fp]
    f32x4 acc[4][8];
#pragma unroll
    for (int kt = 0; kt < 4; ++kt)
#pragma unroll
        for (int qj = 0; qj < 8; ++qj) acc[kt][qj] = (f32x4){0.f, 0.f, 0.f, 0.f};

    char* AbP[3] = {lds, lds + AB_BYTES, lds + 2 * AB_BYTES};
    char* BbP[3] = {lds + 3 * AB_BYTES,
                    lds + 3 * AB_BYTES + BB_BYTES,
                    lds + 3 * AB_BYTES + 2 * BB_BYTES};

#define STAGE(CH, ABUF, BBUF)                                                        \
    {                                                                                \
        const int d0_ = (CH) * 32;                                                   \
        _Pragma("unroll")                                                            \
        for (int q = 0; q < 2; ++q)                                                  \
            load_lds16(Abase + (size_t)a_r[q] * DIM + d0_ + a_cl[q] * 8,             \
                       (ABUF) + q * 4096 + wv * 1024);                               \
        _Pragma("unroll")                                                            \
        for (int q = 0; q < 4; ++q)                                                  \
            load_lds16(Bbase + (size_t)b_r[q] * DIM + d0_ + b_cl[q] * 8,             \
                       (BBUF) + q * 4096 + wv * 1024);                               \
    }

#define COMPUTE(ABUF, BBUF)                                                          \
    {                                                                                \
        short8 kf[4], qf[8];                                                         \
        _Pragma("unroll")                                                            \
        for (int kt = 0; kt < 4; ++kt) {                                             \
            const int r = wv * 64 + kt * 16 + fp;                                    \
            const int cl = fg ^ ((r >> 1) & 3);                                      \
            kf[kt] = *(const short8*)((BBUF) + r * 64 + cl * 16);                    \
        }                                                                            \
        _Pragma("unroll")                                                            \
        for (int qj = 0; qj < 8; ++qj) {                                             \
            const int r = qj * 16 + fp;                                              \
            const int cl = fg ^ ((r >> 1) & 3);                                      \
            qf[qj] = *(const short8*)((ABUF) + r * 64 + cl * 16);                    \
        }                                                                            \
        __builtin_amdgcn_s_setprio(1);                                               \
        _Pragma("unroll")                                                            \
        for (int kt = 0; kt < 4; ++kt)                                               \
            _Pragma("unroll")                                                        \
            for (int qj = 0; qj < 8; ++qj)                                           \
                acc[kt][qj] = __builtin_amdgcn_mfma_f32_16x16x32_bf16(               \
                    kf[kt], qf[qj], acc[kt][qj], 0, 0, 0);                           \
        __builtin_amdgcn_s_setprio(0);                                               \
    }

    // prologue: stage chunks 0..1 (12 staging loads in flight per wave)
    STAGE(0, AbP[0], BbP[0]);
    STAGE(1, AbP[1], BbP[1]);

    // steady state per chunk (single barrier, stage-ahead 2):
#pragma unroll
    for (int ch = 0; ch < 16; ++ch) {
        if (ch <= 14) { asm volatile("s_waitcnt vmcnt(6)" ::: "memory"); }
        else          { asm volatile("s_waitcnt vmcnt(0)" ::: "memory"); }
        __builtin_amdgcn_s_barrier();
        __builtin_amdgcn_sched_barrier(0);
        if (ch + 2 < 16) STAGE(ch + 2, AbP[(ch + 2) % 3], BbP[(ch + 2) % 3]);
        COMPUTE(AbP[ch % 3], BbP[ch % 3]);
        __builtin_amdgcn_sched_barrier(0);
    }

    // ---- tgt values for this wave's 64 keys (L3-hot; short tail) ----
    const float s2 = temperature[b] * (0.04419417382415922f * 1.4426950408889634f);
    const float* tb = tgt + (size_t)b * 3 * NPTS;
    float tv0[4][4], tv1[4][4], tv2[4][4];
#pragma unroll
    for (int kt = 0; kt < 4; ++kt) {
        const int m0 = ms * 256 + wv * 64 + kt * 16 + fg * 4;
        *(float4*)tv0[kt] = *(const float4*)(tb + m0);
        *(float4*)tv1[kt] = *(const float4*)(tb + NPTS + m0);
        *(float4*)tv2[kt] = *(const float4*)(tb + 2 * NPTS + m0);
    }

    // ---- max-free softmax partials over this wave's 64 keys (in-register) ----
    float l[8], a0[8], a1[8], a2[8];
#pragma unroll
    for (int qj = 0; qj < 8; ++qj) { l[qj] = 0.f; a0[qj] = 0.f; a1[qj] = 0.f; a2[qj] = 0.f; }

#pragma unroll
    for (int kt = 0; kt < 4; ++kt) {
#pragma unroll
        for (int qj = 0; qj < 8; ++qj) {
#pragma unroll
            for (int reg = 0; reg < 4; ++reg) {
                const float w = exp2f(acc[kt][qj][reg] * s2);
                l[qj]  += w;
                a0[qj] = fmaf(w, tv0[kt][reg], a0[qj]);
                a1[qj] = fmaf(w, tv1[kt][reg], a1[qj]);
                a2[qj] = fmaf(w, tv2[kt][reg], a2[qj]);
            }
        }
    }

    float* Pb = P + ((size_t)b * 16 + (ms * 4 + wv)) * 4 * NPTS;
#pragma unroll
    for (int qj = 0; qj < 8; ++qj) {
        float lv = l[qj], v0 = a0[qj], v1 = a1[qj], v2 = a2[qj];
        lv += __shfl_xor(lv, 16); lv += __shfl_xor(lv, 32);
        v0 += __shfl_xor(v0, 16); v0 += __shfl_xor(v0, 32);
        v1 += __shfl_xor(v1, 16); v1 += __shfl_xor(v1, 32);
        v2 += __shfl_xor(v2, 16); v2 += __shfl_xor(v2, 32);
        if (fg == 0) {
            const int n = qt * 128 + qj * 16 + fp;
            Pb[0 * NPTS + n] = lv;
            Pb[1 * NPTS + n] = v0;
            Pb[2 * NPTS + n] = v1;
            Pb[3 * NPTS + n] = v2;
        }
    }
}

// ---------------------------------------------------------------------------
// Kernel C1: merge partials -> corr; per-block raw sums (Σs, Σc, Σ s·cᵀ).
// 64 blocks (4 per batch). H = Σ s·cᵀ − N·sm·cmᵀ assembled later in double.
// ---------------------------------------------------------------------------
__global__ __launch_bounds__(256) void merge_partial_kernel(
    const float* __restrict__ P, const float* __restrict__ src,
    float* __restrict__ Pacc)
{
    const int bid = blockIdx.x;
    const int b   = bid >> 2;
    const int seg = bid & 3;
    const int tid = threadIdx.x;
    const int n   = seg * 256 + tid;

    const float* Pb = P + (size_t)b * 16 * 4 * NPTS;
    float l = 0, a0 = 0, a1 = 0, a2 = 0;
    for (int pp = 0; pp < 16; ++pp) {
        const float* q = Pb + (size_t)pp * 4 * NPTS;
        l  += q[n];
        a0 += q[NPTS + n];
        a1 += q[2 * NPTS + n];
        a2 += q[3 * NPTS + n];
    }
    const float inv = 1.0f / l;
    const float c0 = a0 * inv, c1 = a1 * inv, c2 = a2 * inv;

    const float* sp = src + (size_t)b * 3 * NPTS;
    const float s0 = sp[n], s1 = sp[NPTS + n], s2 = sp[2 * NPTS + n];

    float v[15] = { s0, s1, s2, c0, c1, c2,
                    s0 * c0, s0 * c1, s0 * c2,
                    s1 * c0, s1 * c1, s1 * c2,
                    s2 * c0, s2 * c1, s2 * c2 };

#pragma unroll
    for (int off = 1; off < 64; off <<= 1)
#pragma unroll
        for (int k = 0; k < 15; ++k) v[k] += __shfl_xor(v[k], off);

    __shared__ float red[4][15];
    const int wv = tid >> 6;
    if ((tid & 63) == 0)
#pragma unroll
        for (int k = 0; k < 15; ++k) red[wv][k] = v[k];
    __syncthreads();
    if (tid < 15)
        Pacc[bid * 15 + tid] = red[0][tid] + red[1][tid] + red[2][tid] + red[3][tid];
}

// ---------------------------------------------------------------------------
// Kernel C2: final per-batch assembly (double) + Kabsch SVD. 16 tiny blocks.
// ---------------------------------------------------------------------------
__global__ __launch_bounds__(64) void svd_final_kernel(
    const float* __restrict__ Pacc, float* __restrict__ out)
{
    const int b = blockIdx.x;
    if (threadIdx.x != 0) return;

    double s[15];
    for (int k = 0; k < 15; ++k) {
        double acc = 0;
        for (int seg = 0; seg < 4; ++seg)
            acc += (double)Pacc[(b * 4 + seg) * 15 + k];
        s[k] = acc;
    }
    const double invN = 1.0 / (double)NPTS;
    const double sm[3] = {s[0] * invN, s[1] * invN, s[2] * invN};
    const double cm[3] = {s[3] * invN, s[4] * invN, s[5] * invN};
    double H[3][3];
    for (int i = 0; i < 3; ++i)
        for (int jj = 0; jj < 3; ++jj)
            H[i][jj] = s[6 + i * 3 + jj] - (double)NPTS * sm[i] * cm[jj];
    kabsch_from_H(H, sm, cm, out, b);
}

// ---------------------------------------------------------------------------
// Legacy fp32 path (fallback when ws is too small for the bf16 pipeline)
// ---------------------------------------------------------------------------
__global__ __launch_bounds__(256) void flash_corr_kernel(
    const float* __restrict__ src_emb,
    const float* __restrict__ tgt_emb,
    const float* __restrict__ tgt,
    const float* __restrict__ temperature,
    float* __restrict__ corr)
{
    const int bid = blockIdx.x;
    const int b   = bid & 15;
    const int qt  = bid >> 4;
    const int n0  = qt * 64;
    const int tid = threadIdx.x;
    const int tx  = tid & 15;
    const int ty  = tid >> 4;

    const float scale = temperature[b] * (1.0f / sqrtf((float)DIM));

    __shared__ float As[2][32][64];
    __shared__ float Bs[2][32][64];
    __shared__ float Ts[3][64];

    const float* Abase  = src_emb + (size_t)b * DIM * NPTS + n0;
    const float* Bbatch = tgt_emb + (size_t)b * DIM * NPTS;
    const float* Tbatch = tgt     + (size_t)b * 3 * NPTS;

    const int dr0 = tid >> 4;
    const int dr1 = dr0 + 16;
    const int c4  = (tid & 15) * 4;

    float mrun[4], lpart[4], acc0[4], acc1[4], acc2[4];
#pragma unroll
    for (int r = 0; r < 4; ++r) {
        mrun[r] = -1e30f; lpart[r] = 0.0f;
        acc0[r] = 0.0f; acc1[r] = 0.0f; acc2[r] = 0.0f;
    }

    for (int mt = 0; mt < 16; ++mt) {
        const int m0 = mt * 64;
        const float* Bbase = Bbatch + m0;
        __syncthreads();
        if (tid < 192) {
            const int i = tid >> 6, mc = tid & 63;
            Ts[i][mc] = Tbatch[i * NPTS + m0 + mc];
        }
        {
            float4 a0 = *(const float4*)(Abase + (size_t)dr0 * NPTS + c4);
            float4 a1 = *(const float4*)(Abase + (size_t)dr1 * NPTS + c4);
            float4 b0 = *(const float4*)(Bbase + (size_t)dr0 * NPTS + c4);
            float4 b1 = *(const float4*)(Bbase + (size_t)dr1 * NPTS + c4);
            *(float4*)&As[0][dr0][c4] = a0;
            *(float4*)&As[0][dr1][c4] = a1;
            *(float4*)&Bs[0][dr0][c4] = b0;
            *(float4*)&Bs[0][dr1][c4] = b1;
        }
        __syncthreads();

        float S[4][4];
#pragma unroll
        for (int r = 0; r < 4; ++r)
#pragma unroll
            for (int c = 0; c < 4; ++c) S[r][c] = 0.0f;

        for (int ch = 0; ch < 16; ++ch) {
            const int buf = ch & 1;
            float4 a0n, a1n, b0n, b1n;
            if (ch < 15) {
                const float* Ab = Abase + (size_t)(ch + 1) * 32 * NPTS;
                const float* Bb = Bbase + (size_t)(ch + 1) * 32 * NPTS;
                a0n = *(const float4*)(Ab + (size_t)dr0 * NPTS + c4);
                a1n = *(const float4*)(Ab + (size_t)dr1 * NPTS + c4);
                b0n = *(const float4*)(Bb + (size_t)dr0 * NPTS + c4);
                b1n = *(const float4*)(Bb + (size_t)dr1 * NPTS + c4);
            }
#pragma unroll
            for (int dk = 0; dk < 32; ++dk) {
                const float4 av = *(const float4*)(&As[buf][dk][ty * 4]);
                const float4 bv = *(const float4*)(&Bs[buf][dk][tx * 4]);
                S[0][0] = fmaf(av.x, bv.x, S[0][0]);
                S[0][1] = fmaf(av.x, bv.y, S[0][1]);
                S[0][2] = fmaf(av.x, bv.z, S[0][2]);
                S[0][3] = fmaf(av.x, bv.w, S[0][3]);
                S[1][0] = fmaf(av.y, bv.x, S[1][0]);
                S[1][1] = fmaf(av.y, bv.y, S[1][1]);
                S[1][2] = fmaf(av.y, bv.z, S[1][2]);
                S[1][3] = fmaf(av.y, bv.w, S[1][3]);
                S[2][0] = fmaf(av.z, bv.x, S[2][0]);
                S[2][1] = fmaf(av.z, bv.y, S[2][1]);
                S[2][2] = fmaf(av.z, bv.z, S[2][2]);
                S[2][3] = fmaf(av.z, bv.w, S[2][3]);
                S[3][0] = fmaf(av.w, bv.x, S[3][0]);
                S[3][1] = fmaf(av.w, bv.y, S[3][1]);
                S[3][2] = fmaf(av.w, bv.z, S[3][2]);
                S[3][3] = fmaf(av.w, bv.w, S[3][3]);
            }
            __syncthreads();
            if (ch < 15) {
                *(float4*)&As[buf ^ 1][dr0][c4] = a0n;
                *(float4*)&As[buf ^ 1][dr1][c4] = a1n;
                *(float4*)&Bs[buf ^ 1][dr0][c4] = b0n;
                *(float4*)&Bs[buf ^ 1][dr1][c4] = b1n;
                __syncthreads();
            }
        }

#pragma unroll
        for (int r = 0; r < 4; ++r) {
            float z0 = S[r][0] * scale, z1 = S[r][1] * scale;
            float z2 = S[r][2] * scale, z3 = S[r][3] * scale;
            float mt_ = fmaxf(fmaxf(z0, z1), fmaxf(z2, z3));
#pragma unroll
            for (int off = 1; off < 16; off <<= 1)
                mt_ = fmaxf(mt_, __shfl_xor(mt_, off));
            const float mnew = fmaxf(mrun[r], mt_);
            const float f = expf(mrun[r] - mnew);
            lpart[r] *= f; acc0[r] *= f; acc1[r] *= f; acc2[r] *= f;
            const float w0 = expf(z0 - mnew);
            const float w1 = expf(z1 - mnew);
            const float w2 = expf(z2 - mnew);
            const float w3 = expf(z3 - mnew);
            lpart[r] += w0 + w1 + w2 + w3;
            const int mc = tx * 4;
            acc0[r] += w0 * Ts[0][mc] + w1 * Ts[0][mc+1] + w2 * Ts[0][mc+2] + w3 * Ts[0][mc+3];
            acc1[r] += w0 * Ts[1][mc] + w1 * Ts[1][mc+1] + w2 * Ts[1][mc+2] + w3 * Ts[1][mc+3];
            acc2[r] += w0 * Ts[2][mc] + w1 * Ts[2][mc+1] + w2 * Ts[2][mc+2] + w3 * Ts[2][mc+3];
            mrun[r] = mnew;
        }
    }

#pragma unroll
    for (int r = 0; r < 4; ++r) {
        float l = lpart[r], a0 = acc0[r], a1 = acc1[r], a2 = acc2[r];
#pragma unroll
        for (int off = 1; off < 16; off <<= 1) {
            l  += __shfl_xor(l,  off);
            a0 += __shfl_xor(a0, off);
            a1 += __shfl_xor(a1, off);
            a2 += __shfl_xor(a2, off);
        }
        if (tx == 0) {
            const int n = n0 + ty * 4 + r;
            const float inv = 1.0f / l;
            corr[((size_t)b * 3 + 0) * NPTS + n] = a0 * inv;
            corr[((size_t)b * 3 + 1) * NPTS + n] = a1 * inv;
            corr[((size_t)b * 3 + 2) * NPTS + n] = a2 * inv;
        }
    }
}

__global__ __launch_bounds__(256) void reduce_svd_kernel(
    const float* __restrict__ src,
    const float* __restrict__ corr,
    float* __restrict__ out)
{
    const int b = blockIdx.x;
    const int tid = threadIdx.x;

    __shared__ float wred[4][9];
    __shared__ float meansh[6];

    const float* sp = src  + (size_t)b * 3 * NPTS;
    const float* cp = corr + (size_t)b * 3 * NPTS;

    float ss0 = 0, ss1 = 0, ss2 = 0, cs0 = 0, cs1 = 0, cs2 = 0;
    for (int n = tid; n < NPTS; n += 256) {
        ss0 += sp[n]; ss1 += sp[NPTS + n]; ss2 += sp[2 * NPTS + n];
        cs0 += cp[n]; cs1 += cp[NPTS + n]; cs2 += cp[2 * NPTS + n];
    }
#pragma unroll
    for (int off = 1; off < 64; off <<= 1) {
        ss0 += __shfl_xor(ss0, off); ss1 += __shfl_xor(ss1, off); ss2 += __shfl_xor(ss2, off);
        cs0 += __shfl_xor(cs0, off); cs1 += __shfl_xor(cs1, off); cs2 += __shfl_xor(cs2, off);
    }
    const int wave = tid >> 6;
    if ((tid & 63) == 0) {
        wred[wave][0] = ss0; wred[wave][1] = ss1; wred[wave][2] = ss2;
        wred[wave][3] = cs0; wred[wave][4] = cs1; wred[wave][5] = cs2;
    }
    __syncthreads();
    if (tid < 6)
        meansh[tid] = (wred[0][tid] + wred[1][tid] + wred[2][tid] + wred[3][tid]) * (1.0f / NPTS);
    __syncthreads();
    const float sm0 = meansh[0], sm1 = meansh[1], sm2 = meansh[2];
    const float cm0 = meansh[3], cm1 = meansh[4], cm2 = meansh[5];

    float h[9] = {0, 0, 0, 0, 0, 0, 0, 0, 0};
    for (int n = tid; n < NPTS; n += 256) {
        const float a0 = sp[n] - sm0, a1 = sp[NPTS + n] - sm1, a2 = sp[2 * NPTS + n] - sm2;
        const float b0 = cp[n] - cm0, b1 = cp[NPTS + n] - cm1, b2 = cp[2 * NPTS + n] - cm2;
        h[0] += a0 * b0; h[1] += a0 * b1; h[2] += a0 * b2;
        h[3] += a1 * b0; h[4] += a1 * b1; h[5] += a1 * b2;
        h[6] += a2 * b0; h[7] += a2 * b1; h[8] += a2 * b2;
    }
#pragma unroll
    for (int off = 1; off < 64; off <<= 1) {
#pragma unroll
        for (int j = 0; j < 9; ++j) h[j] += __shfl_xor(h[j], off);
    }
    __syncthreads();
    if ((tid & 63) == 0) {
#pragma unroll
        for (int j = 0; j < 9; ++j) wred[wave][j] = h[j];
    }
    __syncthreads();

    if (tid == 0) {
        double H[3][3];
        for (int i = 0; i < 3; ++i)
            for (int j = 0; j < 3; ++j)
                H[i][j] = (double)wred[0][i * 3 + j] + wred[1][i * 3 + j]
                        + wred[2][i * 3 + j] + wred[3][i * 3 + j];
        const double sm[3] = {sm0, sm1, sm2};
        const double cm[3] = {cm0, cm1, cm2};
        kabsch_from_H(H, sm, cm, out, b);
    }
}

extern "C" void kernel_launch(void* const* d_in, const int* in_sizes, int n_in,
                              void* d_out, int out_size, void* d_ws, size_t ws_size,
                              hipStream_t stream) {
    const float* src_emb = (const float*)d_in[0];
    const float* tgt_emb = (const float*)d_in[1];
    const float* src     = (const float*)d_in[2];
    const float* tgt     = (const float*)d_in[3];
    const float* temp    = (const float*)d_in[4];
    float* out = (float*)d_out;

    const size_t AT_BYTES   = (size_t)BATCH * NPTS * DIM * 2;    // 16 MB
    const size_t P_BYTES    = (size_t)BATCH * 16 * 4 * NPTS * 4; // 4 MB
    const size_t PACC_BYTES = 64 * 15 * sizeof(float);

    if (ws_size >= 2 * AT_BYTES + P_BYTES + PACC_BYTES) {
        unsigned short* AT = (unsigned short*)d_ws;
        unsigned short* BT = (unsigned short*)((char*)d_ws + AT_BYTES);
        float* P    = (float*)((char*)d_ws + 2 * AT_BYTES);
        float* Pacc = (float*)((char*)d_ws + 2 * AT_BYTES + P_BYTES);

        transpose_bf16_kernel<<<dim3(2 * BATCH * 8 * 16), dim3(256), 0, stream>>>(
            src_emb, tgt_emb, AT, BT);
        attn_corr_kernel<<<dim3(BATCH * 8 * 4), dim3(256), 0, stream>>>(
            AT, BT, tgt, temp, P);
        merge_partial_kernel<<<dim3(64), dim3(256), 0, stream>>>(P, src, Pacc);
        svd_final_kernel<<<dim3(BATCH), dim3(64), 0, stream>>>(Pacc, out);
    } else {
        float* corr = (float*)d_ws;  // [B][3][N] fp32 = 192 KiB
        flash_corr_kernel<<<dim3(BATCH * (NPTS / 64)), dim3(256), 0, stream>>>(
            src_emb, tgt_emb, tgt, temp, corr);
        reduce_svd_kernel<<<dim3(BATCH), dim3(256), 0, stream>>>(src, corr, out);
    }
}